// Round 8
// baseline (265.738 us; speedup 1.0000x reference)
//
#include <hip/hip_runtime.h>

// VectorQuantizer: x [32,64,64,64] f32, emb [512,64] f32 -> out [32,64,64,64] f32
// R8: MFMA bf16 screening + exact-f32 rescore of provable candidates.
//  - screen: s~[p][k] = e_sq[k] - 2*D, D = mfma_f32_16x16x32_bf16(bf16(x),bf16(e))
//    error bound: |s~ - exact| <= 1.7e-5*sum|x_i| + tiny (bf16 0.5ulp quant,
//    fp32 mfma acc, f16 D storage). np-vs-exact <= ~3e-5.
//  - rescore every k with s~ < s~min + margin, margin = 4e-5*sum|x| + 5e-4
//    (> 2*eps_screen + 2*eps_np for all pixels) with the R2-VERIFIED bit-exact
//    np recipe: d = sequential-c fmaf chain; x_sq/e_sq = pairwise-8;
//    s = fl(fl(xs+e_sq)-fl(2d)); lexicographic (s,k) min = first-occurrence.
//  - MFMA layouts (m89/m120 verified): A/B frag [m|n=lane&15][k=quad*8+j],
//    D row=quad*4+reg (A-dim=pixel), col=lane&15 (B-dim=code).
// Block: 32 pixels, 512 thr (8 waves), each wave a 64-code slice.

#define KNUM 512
#define CDIM 64
#define MPB  32
#define THR  512
#define NSL  (KNUM / 8)     // 64 codes per wave
#define SCS  522            // f16 score row stride (5*row mod 32 -> conflict-free scan)
#define XTS  68             // x row stride (R6-measured 0-conflict for b128)

typedef __attribute__((ext_vector_type(8))) short bf16x8;
typedef __attribute__((ext_vector_type(4))) float f32x4;

__device__ __forceinline__ unsigned short f2bf(float f) {   // RNE f32->bf16
    unsigned u = __float_as_uint(f);
    return (unsigned short)((u + 0x7FFFu + ((u >> 16) & 1u)) >> 16);
}

__device__ __forceinline__ float xsq_pairwise8(const float* xr)
{
    float r[8];
    {
        const float4 a = *(const float4*)&xr[0];
        const float4 c = *(const float4*)&xr[4];
        r[0] = __fmul_rn(a.x, a.x); r[1] = __fmul_rn(a.y, a.y);
        r[2] = __fmul_rn(a.z, a.z); r[3] = __fmul_rn(a.w, a.w);
        r[4] = __fmul_rn(c.x, c.x); r[5] = __fmul_rn(c.y, c.y);
        r[6] = __fmul_rn(c.z, c.z); r[7] = __fmul_rn(c.w, c.w);
    }
    #pragma unroll
    for (int i = 1; i < 8; ++i) {
        const float4 a = *(const float4*)&xr[8 * i];
        const float4 c = *(const float4*)&xr[8 * i + 4];
        r[0] = __fadd_rn(r[0], __fmul_rn(a.x, a.x));
        r[1] = __fadd_rn(r[1], __fmul_rn(a.y, a.y));
        r[2] = __fadd_rn(r[2], __fmul_rn(a.z, a.z));
        r[3] = __fadd_rn(r[3], __fmul_rn(a.w, a.w));
        r[4] = __fadd_rn(r[4], __fmul_rn(c.x, c.x));
        r[5] = __fadd_rn(r[5], __fmul_rn(c.y, c.y));
        r[6] = __fadd_rn(r[6], __fmul_rn(c.z, c.z));
        r[7] = __fadd_rn(r[7], __fmul_rn(c.w, c.w));
    }
    return __fadd_rn(
        __fadd_rn(__fadd_rn(r[0], r[1]), __fadd_rn(r[2], r[3])),
        __fadd_rn(__fadd_rn(r[4], r[5]), __fadd_rn(r[6], r[7])));
}

__global__ __launch_bounds__(256) void vq_prep(const float* __restrict__ emb,
                                               float* __restrict__ e_sq)
{
    const int k = blockIdx.x * 256 + threadIdx.x;
    if (k < KNUM) {
        const float* e = emb + k * CDIM;
        float r[8];
        #pragma unroll
        for (int j = 0; j < 8; ++j) r[j] = __fmul_rn(e[j], e[j]);
        #pragma unroll
        for (int i = 8; i < CDIM; i += 8)
            #pragma unroll
            for (int j = 0; j < 8; ++j)
                r[j] = __fadd_rn(r[j], __fmul_rn(e[i + j], e[i + j]));
        e_sq[k] = __fadd_rn(
            __fadd_rn(__fadd_rn(r[0], r[1]), __fadd_rn(r[2], r[3])),
            __fadd_rn(__fadd_rn(r[4], r[5]), __fadd_rn(r[6], r[7])));
    }
}

__global__ __launch_bounds__(THR) void vq_main(const float* __restrict__ x,
                                               const float* __restrict__ emb,
                                               const float* __restrict__ e_sq,
                                               float* __restrict__ out)
{
    __shared__ float    xt[MPB][XTS];       //  8704 B
    __shared__ _Float16 sc[MPB][SCS];       // 33408 B
    __shared__ float    lesq[KNUM];         //  2048 B
    __shared__ float    rv[16][MPB];        //  2048 B
    __shared__ int      rix[16][MPB];       //  2048 B
    __shared__ float    tthr[MPB], xsq_s[MPB];
    __shared__ int      widx[MPB];

    const int t    = threadIdx.x;
    const int pix0 = blockIdx.x * MPB;
    const int b    = pix0 >> 12;
    const int hw0  = pix0 & 4095;
    const float* xb = x + (((size_t)b * CDIM) << 12) + hw0;

    for (int k = t; k < KNUM; k += THR) lesq[k] = e_sq[k];
    {   // stage x tile (coalesced 32-lane runs), [pixel][channel] in LDS
        const int p = t & 31, cc = t >> 5;
        float4 v;
        v.x = xb[((size_t)(4 * cc + 0) << 12) + p];
        v.y = xb[((size_t)(4 * cc + 1) << 12) + p];
        v.z = xb[((size_t)(4 * cc + 2) << 12) + p];
        v.w = xb[((size_t)(4 * cc + 3) << 12) + p];
        *(float4*)&xt[p][4 * cc] = v;
    }
    __syncthreads();

    // ---------------- MFMA screen: D[p][k] -> sc (f16) ----------------
    {
        const int l  = t & 63;
        const int w  = __builtin_amdgcn_readfirstlane(t >> 6);  // wave id, uniform
        const int i15 = l & 15, quad = l >> 4;
        const int nbase = w * NSL;

        bf16x8 bfr[4][2];                    // B frags: 4 ntiles x 2 k-chunks
        #pragma unroll
        for (int nt = 0; nt < 4; ++nt)
            #pragma unroll
            for (int kc = 0; kc < 2; ++kc) {
                const float* ep = emb + (size_t)(nbase + nt * 16 + i15) * CDIM
                                + quad * 8 + kc * 32;
                const float4 e0 = *(const float4*)ep;
                const float4 e1 = *(const float4*)(ep + 4);
                bf16x8 f;
                f[0] = f2bf(e0.x); f[1] = f2bf(e0.y); f[2] = f2bf(e0.z); f[3] = f2bf(e0.w);
                f[4] = f2bf(e1.x); f[5] = f2bf(e1.y); f[6] = f2bf(e1.z); f[7] = f2bf(e1.w);
                bfr[nt][kc] = f;
            }
        #pragma unroll
        for (int mt = 0; mt < 2; ++mt) {
            bf16x8 af[2];
            #pragma unroll
            for (int kc = 0; kc < 2; ++kc) {
                const float* xp = &xt[mt * 16 + i15][quad * 8 + kc * 32];
                const float4 x0 = *(const float4*)xp;
                const float4 x1 = *(const float4*)(xp + 4);
                bf16x8 f;
                f[0] = f2bf(x0.x); f[1] = f2bf(x0.y); f[2] = f2bf(x0.z); f[3] = f2bf(x0.w);
                f[4] = f2bf(x1.x); f[5] = f2bf(x1.y); f[6] = f2bf(x1.z); f[7] = f2bf(x1.w);
                af[kc] = f;
            }
            #pragma unroll
            for (int nt = 0; nt < 4; ++nt) {
                f32x4 acc = {0.f, 0.f, 0.f, 0.f};
                acc = __builtin_amdgcn_mfma_f32_16x16x32_bf16(af[0], bfr[nt][0], acc, 0, 0, 0);
                acc = __builtin_amdgcn_mfma_f32_16x16x32_bf16(af[1], bfr[nt][1], acc, 0, 0, 0);
                const int kcol = nbase + nt * 16 + i15;
                #pragma unroll
                for (int r = 0; r < 4; ++r)
                    sc[mt * 16 + quad * 4 + r][kcol] = (_Float16)acc[r];
            }
        }
    }
    __syncthreads();

    // ---------------- pass A: per-pixel screen min ----------------
    const int p  = t & 31;
    const int ch = t >> 5;                   // chunk 0..15; thread scans k = ch+16i
    float smin = 3.4e38f;
    #pragma unroll 1
    for (int i = 0; i < 32; ++i) {
        const int k = ch + 16 * i;
        smin = fminf(smin, fmaf(-2.0f, (float)sc[p][k], lesq[k]));
    }
    rv[ch][p] = smin;
    __syncthreads();
    if (t < MPB) {                           // t = pixel
        float m = rv[0][t];
        #pragma unroll
        for (int c = 1; c < 16; ++c) m = fminf(m, rv[c][t]);
        float axs = 0.f;
        for (int c = 0; c < CDIM; ++c) axs += fabsf(xt[t][c]);
        tthr[t]  = m + (4.0e-5f * axs + 5.0e-4f);   // >= 2*eps_screen + 2*eps_np
        xsq_s[t] = xsq_pairwise8(xt[t]);
    }
    __syncthreads();

    // ---------------- pass B: exact rescore of candidates ----------------
    {
        const float thr = tthr[p], xs = xsq_s[p];
        float bs = 3.4e38f; int bk = 0x7fffffff;
        #pragma unroll 1
        for (int i = 0; i < 32; ++i) {
            const int k = ch + 16 * i;
            const float s = fmaf(-2.0f, (float)sc[p][k], lesq[k]);
            if (s < thr) {                   // rare (~2/pixel over all 16 chunks)
                const float* er = emb + (size_t)k * CDIM;
                float d = 0.f;
                #pragma unroll
                for (int c4 = 0; c4 < 16; ++c4) {   // sequential-c fmaf = np order
                    const float4 xv = *(const float4*)&xt[p][4 * c4];
                    const float4 ev = *(const float4*)&er[4 * c4];
                    d = fmaf(xv.x, ev.x, d);
                    d = fmaf(xv.y, ev.y, d);
                    d = fmaf(xv.z, ev.z, d);
                    d = fmaf(xv.w, ev.w, d);
                }
                const float se = __fsub_rn(__fadd_rn(xs, lesq[k]),
                                           __fmul_rn(2.0f, d));
                if (se < bs || (se == bs && k < bk)) { bs = se; bk = k; }
            }
        }
        rv[ch][p] = bs; rix[ch][p] = bk;
    }
    __syncthreads();
    if (t < MPB) {
        float v = rv[0][t]; int kk = rix[0][t];
        #pragma unroll
        for (int c = 1; c < 16; ++c) {
            const float v2 = rv[c][t]; const int k2 = rix[c][t];
            if (v2 < v || (v2 == v && k2 < kk)) { v = v2; kk = k2; }
        }
        widx[t] = kk;
    }
    __syncthreads();

    // ---------------- gather + write (bit-exact emb row copy) ----------------
    {
        const int po = t & 31, cg = t >> 5;  // 4 channels per thread
        const float* er = emb + (size_t)widx[po] * CDIM + 4 * cg;
        float* ob = out + (((size_t)b * CDIM) << 12) + (((size_t)(4 * cg)) << 12) + hw0 + po;
        ob[(size_t)0 << 12] = er[0];
        ob[(size_t)1 << 12] = er[1];
        ob[(size_t)2 << 12] = er[2];
        ob[(size_t)3 << 12] = er[3];
    }
}

extern "C" void kernel_launch(void* const* d_in, const int* in_sizes, int n_in,
                              void* d_out, int out_size, void* d_ws, size_t ws_size,
                              hipStream_t stream)
{
    const float* x   = (const float*)d_in[0];
    const float* emb = (const float*)d_in[1];
    float* out  = (float*)d_out;
    float* e_sq = (float*)d_ws;                    // 512 floats of scratch

    hipLaunchKernelGGL(vq_prep, dim3(2), dim3(256), 0, stream, emb, e_sq);
    const int nblocks = (32 * 64 * 64) / MPB;      // 4096
    hipLaunchKernelGGL(vq_main, dim3(nblocks), dim3(THR), 0, stream,
                       x, emb, e_sq, out);
}

// Round 9
// 243.012 us; speedup vs baseline: 1.0935x; 1.0935x over previous
//
#include <hip/hip_runtime.h>

// VectorQuantizer: x [32,64,64,64] f32, emb [512,64] f32 -> out [32,64,64,64] f32
// Algorithm (R8-verified, absmax==0): bf16 MFMA screen s~[p][k] = e_sq[k]-2*(x.e)
// with margin-gated exact-f32 rescore reproducing numpy bit semantics
// (sequential-c fmaf dot, pairwise-8 x_sq/e_sq, _rn score, lexicographic (s,k)).
// R9 = instruction-count rewrite of R8 (~2700 -> ~400 inst/lane):
//  - emb->bf16 precomputed ONCE in prep (in-order row layout) -> B-frags are
//    plain dwordx4 global loads (R8 reconverted emb in every block: ~770 i/l).
//  - x->bf16 packed during staging into LDS A-frag layout -> ds_read_b128.
//  - screen stores s~ directly (e_sq folded) -> scans are pure mins.
//  - scans use v_pk_min_f16 trees over b128 reads (was scalar u16, unroll-1).
//  - serial axs section -> staged partials + tiny combine.

#define KNUM 512
#define CDIM 64
#define MPB  32
#define THR  512

typedef __attribute__((ext_vector_type(8))) short bf16x8;
typedef __attribute__((ext_vector_type(4))) float f32x4;
typedef _Float16 h2 __attribute__((ext_vector_type(2)));

__device__ __forceinline__ unsigned f2bf(float f) {   // RNE f32->bf16 (16-bit result)
    unsigned u = __float_as_uint(f);
    return (u + 0x7FFFu + ((u >> 16) & 1u)) >> 16;
}

__device__ __forceinline__ float xsq_pairwise8(const float* xr)   // exact np order
{
    float r[8];
    {
        const float4 a = *(const float4*)&xr[0];
        const float4 c = *(const float4*)&xr[4];
        r[0] = __fmul_rn(a.x, a.x); r[1] = __fmul_rn(a.y, a.y);
        r[2] = __fmul_rn(a.z, a.z); r[3] = __fmul_rn(a.w, a.w);
        r[4] = __fmul_rn(c.x, c.x); r[5] = __fmul_rn(c.y, c.y);
        r[6] = __fmul_rn(c.z, c.z); r[7] = __fmul_rn(c.w, c.w);
    }
    #pragma unroll
    for (int i = 1; i < 8; ++i) {
        const float4 a = *(const float4*)&xr[8 * i];
        const float4 c = *(const float4*)&xr[8 * i + 4];
        r[0] = __fadd_rn(r[0], __fmul_rn(a.x, a.x));
        r[1] = __fadd_rn(r[1], __fmul_rn(a.y, a.y));
        r[2] = __fadd_rn(r[2], __fmul_rn(a.z, a.z));
        r[3] = __fadd_rn(r[3], __fmul_rn(a.w, a.w));
        r[4] = __fadd_rn(r[4], __fmul_rn(c.x, c.x));
        r[5] = __fadd_rn(r[5], __fmul_rn(c.y, c.y));
        r[6] = __fadd_rn(r[6], __fmul_rn(c.z, c.z));
        r[7] = __fadd_rn(r[7], __fmul_rn(c.w, c.w));
    }
    return __fadd_rn(
        __fadd_rn(__fadd_rn(r[0], r[1]), __fadd_rn(r[2], r[3])),
        __fadd_rn(__fadd_rn(r[4], r[5]), __fadd_rn(r[6], r[7])));
}

// prep: exact e_sq + bf16 emb (in-order rows, 128 B/row) — once per call
__global__ __launch_bounds__(512) void vq_prep(const float* __restrict__ emb,
                                               float* __restrict__ e_sq,
                                               unsigned* __restrict__ ebf)
{
    const int k = threadIdx.x;               // 512 threads, 1 block
    const float* e = emb + k * CDIM;
    e_sq[k] = xsq_pairwise8(e);
    unsigned buf[32];
    #pragma unroll
    for (int d = 0; d < 32; ++d)
        buf[d] = f2bf(e[2 * d]) | (f2bf(e[2 * d + 1]) << 16);
    uint4* dst = (uint4*)(ebf + k * 32);
    #pragma unroll
    for (int i = 0; i < 8; ++i) dst[i] = ((const uint4*)buf)[i];
}

__global__ __launch_bounds__(THR) void vq_main(const float* __restrict__ x,
                                               const float* __restrict__ emb,
                                               const float* __restrict__ e_sq,
                                               const unsigned* __restrict__ ebf,
                                               float* __restrict__ out)
{
    __shared__ float    xt[MPB][68];         //  8704 B, exact x (stride 68)
    __shared__ _Float16 xbf[MPB][72];        //  4608 B, bf16 x (A-frag reads)
    __shared__ _Float16 sc[MPB][520];        // 33280 B, f16 screen scores
    __shared__ float    lesq[KNUM];          //  2048 B
    __shared__ float    rv[MPB][16];         //  2048 B
    __shared__ short    rix[MPB][16];        //  1024 B
    __shared__ float    axp[MPB][16];        //  2048 B
    __shared__ float    tthr[MPB], xsq_s[MPB];
    __shared__ int      widx[MPB];           // total 54144 B -> 3 blocks/CU

    const int t    = threadIdx.x;
    const int pix0 = blockIdx.x * MPB;
    const int b    = pix0 >> 12;             // H*W=4096, 32|4096: no crossing
    const int hw0  = pix0 & 4095;
    const float* xb = x + (((size_t)b * CDIM) << 12) + hw0;

    // ---- P1: stage x (f32 + packed bf16) + |x| partials + lesq ----
    lesq[t] = e_sq[t];                       // KNUM == THR
    {
        const int p = t & 31, cc = t >> 5;   // pixel, channel-quad
        float4 v;
        v.x = xb[((size_t)(4 * cc + 0) << 12) + p];
        v.y = xb[((size_t)(4 * cc + 1) << 12) + p];
        v.z = xb[((size_t)(4 * cc + 2) << 12) + p];
        v.w = xb[((size_t)(4 * cc + 3) << 12) + p];
        *(float4*)&xt[p][4 * cc] = v;
        uint2 dp;
        dp.x = f2bf(v.x) | (f2bf(v.y) << 16);
        dp.y = f2bf(v.z) | (f2bf(v.w) << 16);
        *(uint2*)&xbf[p][4 * cc] = dp;       // byte off = p*144 + 8*cc, 8-aligned
        axp[p][cc] = fabsf(v.x) + fabsf(v.y) + fabsf(v.z) + fabsf(v.w);
    }
    __syncthreads();

    // ---- P2: MFMA screen, scores (e_sq folded) -> sc ----
    {
        const int l = t & 63;
        const int w = __builtin_amdgcn_readfirstlane(t >> 6);   // uniform
        const int i15 = l & 15, quad = l >> 4;
        const int nbase = w * 64;

        bf16x8 bfr[4][2];
        #pragma unroll
        for (int nt = 0; nt < 4; ++nt)
            #pragma unroll
            for (int kc = 0; kc < 2; ++kc)
                bfr[nt][kc] = *(const bf16x8*)((const char*)ebf
                    + (size_t)(nbase + nt * 16 + i15) * 128 + kc * 64 + quad * 16);
        float eqv[4];
        #pragma unroll
        for (int nt = 0; nt < 4; ++nt) eqv[nt] = lesq[nbase + nt * 16 + i15];

        #pragma unroll
        for (int mt = 0; mt < 2; ++mt) {
            const bf16x8 af0 = *(const bf16x8*)&xbf[mt * 16 + i15][quad * 8];
            const bf16x8 af1 = *(const bf16x8*)&xbf[mt * 16 + i15][quad * 8 + 32];
            #pragma unroll
            for (int nt = 0; nt < 4; ++nt) {
                f32x4 acc = {0.f, 0.f, 0.f, 0.f};
                acc = __builtin_amdgcn_mfma_f32_16x16x32_bf16(af0, bfr[nt][0], acc, 0, 0, 0);
                acc = __builtin_amdgcn_mfma_f32_16x16x32_bf16(af1, bfr[nt][1], acc, 0, 0, 0);
                const int kcol = nbase + nt * 16 + i15;
                #pragma unroll
                for (int r = 0; r < 4; ++r)      // D: row=quad*4+r (pixel), col=i15
                    sc[mt * 16 + quad * 4 + r][kcol] =
                        (_Float16)fmaf(-2.0f, acc[r], eqv[nt]);
            }
        }
    }
    __syncthreads();

    // ---- P3a: packed-min scan (32 scores/thread) ----
    const int p = t & 31, ch = t >> 5;
    {
        const h2* hp = (const h2*)&sc[p][ch * 32];   // 16 x h2, b128-vectorizable
        h2 m = hp[0];
        #pragma unroll
        for (int i = 1; i < 16; ++i) m = __builtin_elementwise_min(m, hp[i]);
        rv[p][ch] = fminf((float)m[0], (float)m[1]);
    }
    __syncthreads();

    // ---- P3b: per-pixel threshold + exact x_sq (32 threads, vectorized) ----
    if (t < MPB) {
        float m = rv[t][0];
        #pragma unroll
        for (int c = 1; c < 16; ++c) m = fminf(m, rv[t][c]);
        float axs = axp[t][0];
        #pragma unroll
        for (int c = 1; c < 16; ++c) axs += axp[t][c];
        tthr[t]  = m + (4.0e-5f * axs + 5.0e-4f);    // >= 2*eps_screen + 2*eps_np
        xsq_s[t] = xsq_pairwise8(xt[t]);
    }
    __syncthreads();

    // ---- P4: candidate rescore (group-skip via packed min) ----
    {
        const float thr = tthr[p], xs = xsq_s[p];
        float bs = 3.4e38f; int bk = 0x7fff;
        const h2* hp = (const h2*)&sc[p][ch * 32];
        #pragma unroll
        for (int g = 0; g < 4; ++g) {
            const h2 m1 = __builtin_elementwise_min(
                __builtin_elementwise_min(hp[4 * g], hp[4 * g + 1]),
                __builtin_elementwise_min(hp[4 * g + 2], hp[4 * g + 3]));
            if (fminf((float)m1[0], (float)m1[1]) < thr) {    // rare
                const _Float16* sp = &sc[p][ch * 32 + g * 8];
                #pragma unroll
                for (int j = 0; j < 8; ++j) {
                    if ((float)sp[j] < thr) {
                        const int kk = ch * 32 + g * 8 + j;
                        const float* er = emb + (size_t)kk * CDIM;
                        float d = 0.f;
                        #pragma unroll
                        for (int c4 = 0; c4 < 16; ++c4) {     // np sequential-c order
                            const float4 xv = *(const float4*)&xt[p][4 * c4];
                            const float4 ev = *(const float4*)&er[4 * c4];
                            d = fmaf(xv.x, ev.x, d);
                            d = fmaf(xv.y, ev.y, d);
                            d = fmaf(xv.z, ev.z, d);
                            d = fmaf(xv.w, ev.w, d);
                        }
                        const float se = __fsub_rn(__fadd_rn(xs, lesq[kk]),
                                                   __fmul_rn(2.0f, d));
                        if (se < bs || (se == bs && kk < bk)) { bs = se; bk = kk; }
                    }
                }
            }
        }
        rv[p][ch] = bs; rix[p][ch] = (short)bk;
    }
    __syncthreads();

    // ---- P4b: lexicographic combine -> winning index ----
    if (t < MPB) {
        float v = rv[t][0]; int kk = rix[t][0];
        #pragma unroll
        for (int c = 1; c < 16; ++c) {
            const float v2 = rv[t][c]; const int k2 = rix[t][c];
            if (v2 < v || (v2 == v && k2 < kk)) { v = v2; kk = k2; }
        }
        widx[t] = kk;
    }
    __syncthreads();

    // ---- P5: gather emb row (bit-exact) -> [B,C,H,W] ----
    {
        const int po = t & 31, cg = t >> 5;
        const float4 ev = *(const float4*)(emb + (size_t)widx[po] * CDIM + 4 * cg);
        float* ob = out + (((size_t)b * CDIM) << 12) + (((size_t)(4 * cg)) << 12) + hw0 + po;
        ob[(size_t)0 << 12] = ev.x;
        ob[(size_t)1 << 12] = ev.y;
        ob[(size_t)2 << 12] = ev.z;
        ob[(size_t)3 << 12] = ev.w;
    }
}

extern "C" void kernel_launch(void* const* d_in, const int* in_sizes, int n_in,
                              void* d_out, int out_size, void* d_ws, size_t ws_size,
                              hipStream_t stream)
{
    const float* x   = (const float*)d_in[0];
    const float* emb = (const float*)d_in[1];
    float* out  = (float*)d_out;
    float*    e_sq = (float*)d_ws;                 // 2 KB
    unsigned* ebf  = (unsigned*)d_ws + KNUM;       // 64 KB bf16 emb

    hipLaunchKernelGGL(vq_prep, dim3(1), dim3(512), 0, stream, emb, e_sq, ebf);
    const int nblocks = (32 * 64 * 64) / MPB;      // 4096
    hipLaunchKernelGGL(vq_main, dim3(nblocks), dim3(THR), 0, stream,
                       x, emb, e_sq, ebf, out);
}

// Round 10
// 143.751 us; speedup vs baseline: 1.8486x; 1.6905x over previous
//
#include <hip/hip_runtime.h>

// VectorQuantizer: x [32,64,64,64] f32, emb [512,64] f32 -> out [32,64,64,64] f32
// Algorithm (R8/R9-verified, absmax==0): bf16 MFMA screen s~ = e_sq - 2*(x.e),
// margin-gated exact-f32 rescore with numpy bit semantics (sequential-c fmaf
// dot, pairwise-8 sums, _rn score, lexicographic (s,k) = first-occurrence).
// R10: register-resident screen. R9 was latency-bound (VALU 22%, MFMA 2%,
// HBM 4% all idle): the f16 score LDS array forced 7 barrier phases + serial
// sections + LDS scan chains. Now scores never leave VGPRs:
//   - nt-fold + __shfl_xor min tree -> one ordered-u32 LDS atomicMin per row
//   - candidates = re-check of register scores vs thr, pushed to LDS queue
//   - exact rescore combines via u64 atomicMin (ordered(se)<<32 | k)
// 5 barriers, no 33KB sc, LDS ~22KB.

#define KNUM 512
#define CDIM 64
#define MPB  32
#define THR  512
#define QCAP 512

typedef __attribute__((ext_vector_type(8))) short bf16x8;
typedef __attribute__((ext_vector_type(4))) float f32x4;

__device__ __forceinline__ unsigned f2bf(float f) {   // RNE f32->bf16
    unsigned u = __float_as_uint(f);
    return (u + 0x7FFFu + ((u >> 16) & 1u)) >> 16;
}
__device__ __forceinline__ unsigned ordf(float f) {   // total-order encode
    unsigned u = __float_as_uint(f);
    return u ^ ((unsigned)(((int)u) >> 31) | 0x80000000u);
}
__device__ __forceinline__ float ordinv(unsigned u) {
    unsigned fb = (u & 0x80000000u) ? (u ^ 0x80000000u) : ~u;
    return __uint_as_float(fb);
}

__device__ __forceinline__ float xsq_pairwise8(const float* xr)   // np order
{
    float r[8];
    {
        const float4 a = *(const float4*)&xr[0];
        const float4 c = *(const float4*)&xr[4];
        r[0] = __fmul_rn(a.x, a.x); r[1] = __fmul_rn(a.y, a.y);
        r[2] = __fmul_rn(a.z, a.z); r[3] = __fmul_rn(a.w, a.w);
        r[4] = __fmul_rn(c.x, c.x); r[5] = __fmul_rn(c.y, c.y);
        r[6] = __fmul_rn(c.z, c.z); r[7] = __fmul_rn(c.w, c.w);
    }
    #pragma unroll
    for (int i = 1; i < 8; ++i) {
        const float4 a = *(const float4*)&xr[8 * i];
        const float4 c = *(const float4*)&xr[8 * i + 4];
        r[0] = __fadd_rn(r[0], __fmul_rn(a.x, a.x));
        r[1] = __fadd_rn(r[1], __fmul_rn(a.y, a.y));
        r[2] = __fadd_rn(r[2], __fmul_rn(a.z, a.z));
        r[3] = __fadd_rn(r[3], __fmul_rn(a.w, a.w));
        r[4] = __fadd_rn(r[4], __fmul_rn(c.x, c.x));
        r[5] = __fadd_rn(r[5], __fmul_rn(c.y, c.y));
        r[6] = __fadd_rn(r[6], __fmul_rn(c.z, c.z));
        r[7] = __fadd_rn(r[7], __fmul_rn(c.w, c.w));
    }
    return __fadd_rn(
        __fadd_rn(__fadd_rn(r[0], r[1]), __fadd_rn(r[2], r[3])),
        __fadd_rn(__fadd_rn(r[4], r[5]), __fadd_rn(r[6], r[7])));
}

__global__ __launch_bounds__(512) void vq_prep(const float* __restrict__ emb,
                                               float* __restrict__ e_sq,
                                               unsigned* __restrict__ ebf)
{
    const int k = threadIdx.x;
    const float* e = emb + k * CDIM;
    e_sq[k] = xsq_pairwise8(e);
    unsigned buf[32];
    #pragma unroll
    for (int d = 0; d < 32; ++d)
        buf[d] = f2bf(e[2 * d]) | (f2bf(e[2 * d + 1]) << 16);
    uint4* dst = (uint4*)(ebf + k * 32);
    #pragma unroll
    for (int i = 0; i < 8; ++i) dst[i] = ((const uint4*)buf)[i];
}

__global__ __launch_bounds__(THR) void vq_main(const float* __restrict__ x,
                                               const float* __restrict__ emb,
                                               const float* __restrict__ e_sq,
                                               const unsigned* __restrict__ ebf,
                                               float* __restrict__ out)
{
    __shared__ float    xt[MPB][68];         // 8704 B exact x
    __shared__ _Float16 xbf[MPB][72];        // 4608 B bf16 x (A-frags)
    __shared__ float    lesq[KNUM];          // 2048 B
    __shared__ float    axp[MPB][16];        // 2048 B |x| partials
    __shared__ unsigned pmin[MPB];           // ordered screen min
    __shared__ float    thr[MPB];
    __shared__ unsigned long long bestpk[MPB];
    __shared__ int      cand[QCAP];
    __shared__ int      ccnt;

    const int t    = threadIdx.x;
    const int pix0 = blockIdx.x * MPB;
    const int b    = pix0 >> 12;
    const int hw0  = pix0 & 4095;
    const float* xb = x + (((size_t)b * CDIM) << 12) + hw0;

    // ---- P1: init + stage x (f32 + bf16) + partials + lesq ----
    if (t < MPB) { pmin[t] = 0xFFFFFFFFu; bestpk[t] = ~0ull; }
    if (t == 0) ccnt = 0;
    lesq[t] = e_sq[t];
    {
        const int p = t & 31, cc = t >> 5;
        float4 v;
        v.x = xb[((size_t)(4 * cc + 0) << 12) + p];
        v.y = xb[((size_t)(4 * cc + 1) << 12) + p];
        v.z = xb[((size_t)(4 * cc + 2) << 12) + p];
        v.w = xb[((size_t)(4 * cc + 3) << 12) + p];
        *(float4*)&xt[p][4 * cc] = v;
        uint2 dp;
        dp.x = f2bf(v.x) | (f2bf(v.y) << 16);
        dp.y = f2bf(v.z) | (f2bf(v.w) << 16);
        *(uint2*)&xbf[p][4 * cc] = dp;
        axp[p][cc] = fabsf(v.x) + fabsf(v.y) + fabsf(v.z) + fabsf(v.w);
    }
    __syncthreads();

    // ---- P2: MFMA screen, scores stay in VGPRs ----
    const int l    = t & 63;
    const int w    = __builtin_amdgcn_readfirstlane(t >> 6);  // uniform wave id
    const int i15  = l & 15, quad = l >> 4;
    const int nbase = w * 64;

    float s[2][4][4];                        // [mt][nt][r]
    {
        float eqv[4];
        #pragma unroll
        for (int nt = 0; nt < 4; ++nt) eqv[nt] = lesq[nbase + nt * 16 + i15];
        #pragma unroll
        for (int ntc = 0; ntc < 2; ++ntc) {  // 2-chunk bfr to cap VGPRs
            bf16x8 bfr[2][2];
            #pragma unroll
            for (int nn = 0; nn < 2; ++nn)
                #pragma unroll
                for (int kc = 0; kc < 2; ++kc)
                    bfr[nn][kc] = *(const bf16x8*)((const char*)ebf
                        + (size_t)(nbase + (ntc * 2 + nn) * 16 + i15) * 128
                        + kc * 64 + quad * 16);
            #pragma unroll
            for (int mt = 0; mt < 2; ++mt) {
                const bf16x8 af0 = *(const bf16x8*)&xbf[mt * 16 + i15][quad * 8];
                const bf16x8 af1 = *(const bf16x8*)&xbf[mt * 16 + i15][quad * 8 + 32];
                #pragma unroll
                for (int nn = 0; nn < 2; ++nn) {
                    f32x4 acc = {0.f, 0.f, 0.f, 0.f};
                    acc = __builtin_amdgcn_mfma_f32_16x16x32_bf16(af0, bfr[nn][0], acc, 0, 0, 0);
                    acc = __builtin_amdgcn_mfma_f32_16x16x32_bf16(af1, bfr[nn][1], acc, 0, 0, 0);
                    const int nt = ntc * 2 + nn;
                    #pragma unroll
                    for (int r = 0; r < 4; ++r)      // row=quad*4+r, col=i15
                        s[mt][nt][r] = fmaf(-2.0f, acc[r], eqv[nt]);
                }
            }
        }
    }
    // per-row slice min: nt-fold, then shfl-xor across the 16 col lanes
    #pragma unroll
    for (int mt = 0; mt < 2; ++mt)
        #pragma unroll
        for (int r = 0; r < 4; ++r) {
            float v = fminf(fminf(s[mt][0][r], s[mt][1][r]),
                            fminf(s[mt][2][r], s[mt][3][r]));
            v = fminf(v, __shfl_xor(v, 1));
            v = fminf(v, __shfl_xor(v, 2));
            v = fminf(v, __shfl_xor(v, 4));
            v = fminf(v, __shfl_xor(v, 8));
            if (i15 == 0) atomicMin(&pmin[mt * 16 + quad * 4 + r], ordf(v));
        }
    __syncthreads();

    // ---- P3: per-pixel threshold (32 lanes, tiny) ----
    if (t < MPB) {
        float ax = axp[t][0];
        #pragma unroll
        for (int c = 1; c < 16; ++c) ax += axp[t][c];
        thr[t] = ordinv(pmin[t]) + (4.0e-5f * ax + 5.0e-4f);
    }
    __syncthreads();

    // ---- P4: candidate detection from register scores ----
    {
        float tr[2][4];
        #pragma unroll
        for (int mt = 0; mt < 2; ++mt)
            #pragma unroll
            for (int r = 0; r < 4; ++r) tr[mt][r] = thr[mt * 16 + quad * 4 + r];
        #pragma unroll
        for (int mt = 0; mt < 2; ++mt)
            #pragma unroll
            for (int nt = 0; nt < 4; ++nt)
                #pragma unroll
                for (int r = 0; r < 4; ++r)
                    if (s[mt][nt][r] < tr[mt][r]) {          // rare
                        const int idx = atomicAdd(&ccnt, 1);
                        if (idx < QCAP)
                            cand[idx] = ((mt * 16 + quad * 4 + r) << 16)
                                      | (nbase + nt * 16 + i15);
                    }
    }
    __syncthreads();

    // ---- P5: exact np-semantics rescore of candidates ----
    {
        const int n = min(ccnt, QCAP);
        if (t < n) {
            const int pk = cand[t];
            const int p  = pk >> 16, k = pk & 0xFFFF;
            const float xs = xsq_pairwise8(xt[p]);
            const float* er = emb + (size_t)k * CDIM;
            float d = 0.f;
            #pragma unroll
            for (int c4 = 0; c4 < 16; ++c4) {    // sequential-c fmaf = np order
                const float4 xv = *(const float4*)&xt[p][4 * c4];
                const float4 ev = *(const float4*)&er[4 * c4];
                d = fmaf(xv.x, ev.x, d);
                d = fmaf(xv.y, ev.y, d);
                d = fmaf(xv.z, ev.z, d);
                d = fmaf(xv.w, ev.w, d);
            }
            const float se = __fsub_rn(__fadd_rn(xs, lesq[k]),
                                       __fmul_rn(2.0f, d));
            const unsigned long long pkd =
                ((unsigned long long)ordf(se) << 32) | (unsigned)k;
            atomicMin(&bestpk[p], pkd);          // lexicographic (se, k)
        }
    }
    __syncthreads();

    // ---- P6: gather winning emb row (bit-exact) -> [B,C,H,W] ----
    {
        const int po = t & 31, cg = t >> 5;
        const int wi = (int)(bestpk[po] & 0xFFFFu);
        const float4 ev = *(const float4*)(emb + (size_t)wi * CDIM + 4 * cg);
        float* ob = out + (((size_t)b * CDIM) << 12) + (((size_t)(4 * cg)) << 12) + hw0 + po;
        ob[(size_t)0 << 12] = ev.x;
        ob[(size_t)1 << 12] = ev.y;
        ob[(size_t)2 << 12] = ev.z;
        ob[(size_t)3 << 12] = ev.w;
    }
}

extern "C" void kernel_launch(void* const* d_in, const int* in_sizes, int n_in,
                              void* d_out, int out_size, void* d_ws, size_t ws_size,
                              hipStream_t stream)
{
    const float* x   = (const float*)d_in[0];
    const float* emb = (const float*)d_in[1];
    float* out  = (float*)d_out;
    float*    e_sq = (float*)d_ws;                 // 2 KB
    unsigned* ebf  = (unsigned*)d_ws + KNUM;       // 64 KB bf16 emb

    hipLaunchKernelGGL(vq_prep, dim3(1), dim3(512), 0, stream, emb, e_sq, ebf);
    const int nblocks = (32 * 64 * 64) / MPB;      // 4096
    hipLaunchKernelGGL(vq_main, dim3(nblocks), dim3(THR), 0, stream,
                       x, emb, e_sq, ebf, out);
}